// Round 8
// baseline (111080.286 us; speedup 1.0000x reference)
//
#include <hip/hip_runtime.h>
#include <stdint.h>

#define N_STEPS 2000
#define DT_F 0.01f

typedef float f32x2 __attribute__((ext_vector_type(2)));

// tanh(x) = 1 - 2/(exp2(2x*log2e)+1): mul, exp2, add, rcp, fma = 5 VALU.
__device__ __forceinline__ float fast_tanh(float x) {
    float e = __builtin_amdgcn_exp2f(x * 2.8853900817779268f);  // e^{2x}
    float r = __builtin_amdgcn_rcpf(e + 1.0f);
    return fmaf(-2.0f, r, 1.0f);
}

// acc.{x,y} += h.{x,y} * w.{x,y} — one VOP3P instr, all-VGPR operands.
#define PKFMA(acc, hp, wp) \
    asm("v_pk_fma_f32 %0, %1, %2, %0" : "+v"(acc) : "v"(hp), "v"(wp))
// dst = h*w + c  (3-address: kills accumulator-init movs)
#define PKFMA3(dst, hp, wp, cc) \
    asm("v_pk_fma_f32 %0, %1, %2, %3" : "=v"(dst) : "v"(hp), "v"(wp), "v"(cc))
// dst = h*w + 0  (inline constant 0 as src2)
#define PKFMA0(dst, hp, wp) \
    asm("v_pk_fma_f32 %0, %1, %2, 0" : "=v"(dst) : "v"(hp), "v"(wp))

template <int CTRL>
__device__ __forceinline__ float dpp_add(float v) {
    return v + __builtin_bit_cast(float, __builtin_amdgcn_update_dpp(
                   0, __builtin_bit_cast(int, v), CTRL, 0xf, 0xf, true));
}

// Every lane gets the sum of its row of 16 (all source lanes valid).
__device__ __forceinline__ float row16_sum(float v) {
    v = dpp_add<0xB1>(v);   // quad_perm [1,0,3,2]
    v = dpp_add<0x4E>(v);   // quad_perm [2,3,0,1]
    v = dpp_add<0x124>(v);  // row_ror:4
    v = dpp_add<0x128>(v);  // row_ror:8
    return v;
}

__device__ __forceinline__ float bperm_add(float v, int addr) {
    return v + __builtin_bit_cast(float, __builtin_amdgcn_ds_bpermute(
                   addr, __builtin_bit_cast(int, v)));
}

// Sum across 64 lanes, result uniform in a VGPR (no readlane, no SGPR movs).
__device__ __forceinline__ float wave_sum_u(float v, int a16, int a32) {
    v = row16_sum(v);
    v = bperm_add(v, a16);  // + other row in 32-half
    v = bperm_add(v, a32);  // + other half
    return v;
}

// One-time 64x64 transpose of W2 into workspace: W2T[j][i] = W2[i][j].
// Makes lane j's weight column contiguous -> K-loop streams merged dwordx4
// loads from a 16 KB L1-resident table (instead of 64 strided scalar loads
// or scratch-spill reloads).
__global__ void transpose_w2_kernel(const float* __restrict__ W2,
                                    float* __restrict__ W2T) {
    for (int k = threadIdx.x; k < 64 * 64; k += 256) {
        int i = k >> 6, j = k & 63;
        W2T[j * 64 + i] = W2[k];
    }
}

__global__ __launch_bounds__(256, 8) void node_rk4_kernel(
    const float* __restrict__ y0_in,
    const float* __restrict__ W1, const float* __restrict__ B1,
    const float* __restrict__ W2T, const float* __restrict__ B2,
    const float* __restrict__ W3, const float* __restrict__ B3,
    float* __restrict__ out, int batch)
{
    __shared__ __align__(16) float hl_all[4][64];

    const int tid  = threadIdx.x;
    const int lane = tid & 63;
    const int wib  = tid >> 6;                 // wave-in-block 0..3
    const int b    = blockIdx.x * 4 + wib;     // sample id
    if (b >= batch) return;

    const int j = lane;
    const float w1_0 = W1[j], w1_1 = W1[64 + j];
    const float b1v  = B1[j];
    const float w3_0 = W3[2 * j], w3_1 = W3[2 * j + 1];
    // Fold b3 into lane 0's pre-reduction term.
    const float b3l0 = (lane == 0) ? B3[0] : 0.0f;
    const float b3l1 = (lane == 0) ? B3[1] : 0.0f;
    f32x2 bcon;                                 // {B2[j], 0} — C-operand of first pk_fma
    bcon.x = B2[j];
    bcon.y = 0.0f;

    // Lane j's contiguous weight column (pairs over K). The compiler streams
    // these from L1 inside the loop (merged b64/b128 loads) — deliberately NOT
    // register-resident: at 64-VGPR budget (8 waves/SIMD) that's the win.
    const f32x2* __restrict__ w2c = (const f32x2*)(W2T + (j << 6));

    // bpermute lane-select addresses (bytes = lane*4).
    const int a16 = ((lane ^ 16) << 2);
    const int a32 = ((lane ^ 32) << 2);

    float y0 = y0_in[2 * b + 0];
    float y1 = y0_in[2 * b + 1];

    float* outb = out + (size_t)b * (2 * (N_STEPS + 1));
    if (lane == 0) {
        reinterpret_cast<float2*>(outb)[0] = make_float2(y0, y1);
    }

    const float chdt = 0.5f * DT_F, cdt = DT_F, cdt6 = DT_F / 6.0f;

    float* hl = hl_all[wib];
    const f32x2* hp2 = (const f32x2*)hl;

    // net: wave-uniform (yi0,yi1) -> wave-uniform VGPR (o0,o1); lane j owns unit j.
    auto net = [&](float yi0, float yi1, float& o0, float& o1) {
        float pre = fmaf(yi0, w1_0, fmaf(yi1, w1_1, b1v));
        float h1  = fast_tanh(pre);
        hl[lane] = h1;
        __builtin_amdgcn_wave_barrier();   // write -> read ordering (in-wave DS order)

        f32x2 acc0, acc1, acc2, acc3;
        {
            f32x2 ha = hp2[0], hb = hp2[1], hc = hp2[2], hd = hp2[3];
            f32x2 wa = w2c[0], wb = w2c[1], wc = w2c[2], wd = w2c[3];
            PKFMA3(acc0, ha, wa, bcon);
            PKFMA0(acc1, hb, wb);
            PKFMA0(acc2, hc, wc);
            PKFMA0(acc3, hd, wd);
        }
        #pragma unroll
        for (int i = 4; i < 32; i += 4) {
            f32x2 ha = hp2[i], hb = hp2[i + 1], hc = hp2[i + 2], hd = hp2[i + 3];
            f32x2 wa = w2c[i], wb = w2c[i + 1], wc = w2c[i + 2], wd = w2c[i + 3];
            PKFMA(acc0, ha, wa);
            PKFMA(acc1, hb, wb);
            PKFMA(acc2, hc, wc);
            PKFMA(acc3, hd, wd);
        }
        __builtin_amdgcn_wave_barrier();   // reads done before next eval's write

        f32x2 s = (acc0 + acc1) + (acc2 + acc3);
        float h2 = fast_tanh(s.x + s.y);
        float p0 = fmaf(h2, w3_0, b3l0);
        float p1 = fmaf(h2, w3_1, b3l1);
        o0 = wave_sum_u(p0, a16, a32);
        o1 = wave_sum_u(p1, a16, a32);
    };

    for (int t = 1; t <= N_STEPS; ++t) {
        float k10, k11, k20, k21, k30, k31, k40, k41;
        net(y0, y1, k10, k11);
        net(fmaf(chdt, k10, y0), fmaf(chdt, k11, y1), k20, k21);
        net(fmaf(chdt, k20, y0), fmaf(chdt, k21, y1), k30, k31);
        net(fmaf(cdt,  k30, y0), fmaf(cdt,  k31, y1), k40, k41);
        float s0 = (k10 + k40) + 2.0f * (k20 + k30);
        float s1 = (k11 + k41) + 2.0f * (k21 + k31);
        y0 = fmaf(cdt6, s0, y0);
        y1 = fmaf(cdt6, s1, y1);
        if (lane == 0) {
            reinterpret_cast<float2*>(outb)[t] = make_float2(y0, y1);
        }
    }
}

extern "C" void kernel_launch(void* const* d_in, const int* in_sizes, int n_in,
                              void* d_out, int out_size, void* d_ws, size_t ws_size,
                              hipStream_t stream) {
    const float* y0 = (const float*)d_in[0];
    const float* W1 = (const float*)d_in[1];
    const float* B1 = (const float*)d_in[2];
    const float* W2 = (const float*)d_in[3];
    const float* B2 = (const float*)d_in[4];
    const float* W3 = (const float*)d_in[5];
    const float* B3 = (const float*)d_in[6];
    float* out = (float*)d_out;
    float* W2T = (float*)d_ws;   // 16 KB of workspace

    const int batch = in_sizes[0] / 2;
    const int blocks = (batch + 3) / 4;   // 4 waves (samples) per 256-thread block

    transpose_w2_kernel<<<1, 256, 0, stream>>>(W2, W2T);
    node_rk4_kernel<<<blocks, 256, 0, stream>>>(y0, W1, B1, W2T, B2, W3, B3, out, batch);
}

// Round 9
// 11614.854 us; speedup vs baseline: 9.5636x; 9.5636x over previous
//
#include <hip/hip_runtime.h>
#include <stdint.h>

#define N_STEPS 2000
#define DT_F 0.01f

typedef float f32x2 __attribute__((ext_vector_type(2)));

// tanh(x) = 1 - 2/(exp2(2x*log2e)+1): mul, exp2, add, rcp, fma = 5 VALU.
__device__ __forceinline__ float fast_tanh(float x) {
    float e = __builtin_amdgcn_exp2f(x * 2.8853900817779268f);  // e^{2x}
    float r = __builtin_amdgcn_rcpf(e + 1.0f);
    return fmaf(-2.0f, r, 1.0f);
}

// acc.{x,y} += h.{x,y} * w.{x,y} — one VOP3P instr, all-VGPR operands.
#define PKFMA(acc, hp, wp) \
    asm("v_pk_fma_f32 %0, %1, %2, %0" : "+v"(acc) : "v"(hp), "v"(wp))
// dst = h*w + c  (3-address: kills accumulator-init movs)
#define PKFMA3(dst, hp, wp, cc) \
    asm("v_pk_fma_f32 %0, %1, %2, %3" : "=v"(dst) : "v"(hp), "v"(wp), "v"(cc))
// dst = h*w + 0  (inline constant 0 as src2)
#define PKFMA0(dst, hp, wp) \
    asm("v_pk_fma_f32 %0, %1, %2, 0" : "=v"(dst) : "v"(hp), "v"(wp))

template <int CTRL>
__device__ __forceinline__ float dpp_add(float v) {
    return v + __builtin_bit_cast(float, __builtin_amdgcn_update_dpp(
                   0, __builtin_bit_cast(int, v), CTRL, 0xf, 0xf, true));
}

// Every lane gets the sum of its row of 16 (all source lanes valid).
__device__ __forceinline__ float row16_sum(float v) {
    v = dpp_add<0xB1>(v);   // quad_perm [1,0,3,2]
    v = dpp_add<0x4E>(v);   // quad_perm [2,3,0,1]
    v = dpp_add<0x124>(v);  // row_ror:4
    v = dpp_add<0x128>(v);  // row_ror:8
    return v;
}

__device__ __forceinline__ float bperm_add(float v, int addr) {
    return v + __builtin_bit_cast(float, __builtin_amdgcn_ds_bpermute(
                   addr, __builtin_bit_cast(int, v)));
}

// Sum across 64 lanes, result uniform in a VGPR (no readlane, no SGPR movs).
__device__ __forceinline__ float wave_sum_u(float v, int a16, int a32) {
    v = row16_sum(v);
    v = bperm_add(v, a16);  // + other row in 32-half
    v = bperm_add(v, a32);  // + other half
    return v;
}

// One-time 64x64 transpose of W2 into workspace: W2T[j][i] = W2[i][j].
// Lane j's weight column becomes contiguous -> the one-time register fill is
// 16 merged dwordx4 loads per lane.
__global__ void transpose_w2_kernel(const float* __restrict__ W2,
                                    float* __restrict__ W2T) {
    for (int k = threadIdx.x; k < 64 * 64; k += 256) {
        int i = k >> 6, j = k & 63;
        W2T[j * 64 + i] = W2[k];
    }
}

// min-waves/EU = 3 -> ~170 VGPR budget: the 64 weight regs + ~60 working set
// fit in ARCH VGPRs with headroom, so the allocator has no reason to AGPR-park
// or remat them (the R2-R8 failure mode: VGPR_Count 32-60, weights never
// register-resident, +130-170 VALU cyc/eval of shuffle/addressing overhead).
__global__ __launch_bounds__(256, 3) void node_rk4_kernel(
    const float* __restrict__ y0_in,
    const float* __restrict__ W1, const float* __restrict__ B1,
    const float* __restrict__ W2T, const float* __restrict__ B2,
    const float* __restrict__ W3, const float* __restrict__ B3,
    float* __restrict__ out, int batch)
{
    __shared__ __align__(16) float hl_all[4][64];

    const int tid  = threadIdx.x;
    const int lane = tid & 63;
    const int wib  = tid >> 6;                 // wave-in-block 0..3
    const int b    = blockIdx.x * 4 + wib;     // sample id
    if (b >= batch) return;

    const int j = lane;
    const float w1_0 = W1[j], w1_1 = W1[64 + j];
    const float b1v  = B1[j];
    const float w3_0 = W3[2 * j], w3_1 = W3[2 * j + 1];
    // Fold b3 into lane 0's pre-reduction term.
    const float b3l0 = (lane == 0) ? B3[0] : 0.0f;
    const float b3l1 = (lane == 0) ? B3[1] : 0.0f;
    f32x2 bcon;                                 // {B2[j], 0} — C-operand of first pk_fma
    bcon.x = B2[j];
    bcon.y = 0.0f;

    // Lane j's weight column -> 32 f32x2 register pairs, loaded once.
    f32x2 w2p[32];
    {
        const f32x2* __restrict__ w2c = (const f32x2*)(W2T + (j << 6));
        #pragma unroll
        for (int i = 0; i < 32; ++i) w2p[i] = w2c[i];
    }

    // bpermute lane-select addresses (bytes = lane*4).
    const int a16 = ((lane ^ 16) << 2);
    const int a32 = ((lane ^ 32) << 2);

    float y0 = y0_in[2 * b + 0];
    float y1 = y0_in[2 * b + 1];

    float* outb = out + (size_t)b * (2 * (N_STEPS + 1));
    if (lane == 0) {
        reinterpret_cast<float2*>(outb)[0] = make_float2(y0, y1);
    }

    const float chdt = 0.5f * DT_F, cdt = DT_F, cdt6 = DT_F / 6.0f;

    float* hl = hl_all[wib];
    const f32x2* hp2 = (const f32x2*)hl;

    // net: wave-uniform (yi0,yi1) -> wave-uniform VGPR (o0,o1); lane j owns unit j.
    auto net = [&](float yi0, float yi1, float& o0, float& o1) {
        float pre = fmaf(yi0, w1_0, fmaf(yi1, w1_1, b1v));
        float h1  = fast_tanh(pre);
        hl[lane] = h1;
        __builtin_amdgcn_wave_barrier();   // write -> read ordering (in-wave DS order)

        f32x2 acc0, acc1, acc2, acc3;
        {
            f32x2 ha = hp2[0], hb = hp2[1], hc = hp2[2], hd = hp2[3];
            PKFMA3(acc0, ha, w2p[0], bcon);
            PKFMA0(acc1, hb, w2p[1]);
            PKFMA0(acc2, hc, w2p[2]);
            PKFMA0(acc3, hd, w2p[3]);
        }
        #pragma unroll
        for (int i = 4; i < 32; i += 4) {
            f32x2 ha = hp2[i], hb = hp2[i + 1], hc = hp2[i + 2], hd = hp2[i + 3];
            PKFMA(acc0, ha, w2p[i]);
            PKFMA(acc1, hb, w2p[i + 1]);
            PKFMA(acc2, hc, w2p[i + 2]);
            PKFMA(acc3, hd, w2p[i + 3]);
        }
        __builtin_amdgcn_wave_barrier();   // reads done before next eval's write

        f32x2 s = (acc0 + acc1) + (acc2 + acc3);
        float h2 = fast_tanh(s.x + s.y);
        float p0 = fmaf(h2, w3_0, b3l0);
        float p1 = fmaf(h2, w3_1, b3l1);
        o0 = wave_sum_u(p0, a16, a32);
        o1 = wave_sum_u(p1, a16, a32);
    };

    for (int t = 1; t <= N_STEPS; ++t) {
        float k10, k11, k20, k21, k30, k31, k40, k41;
        net(y0, y1, k10, k11);
        net(fmaf(chdt, k10, y0), fmaf(chdt, k11, y1), k20, k21);
        net(fmaf(chdt, k20, y0), fmaf(chdt, k21, y1), k30, k31);
        net(fmaf(cdt,  k30, y0), fmaf(cdt,  k31, y1), k40, k41);
        float s0 = (k10 + k40) + 2.0f * (k20 + k30);
        float s1 = (k11 + k41) + 2.0f * (k21 + k31);
        y0 = fmaf(cdt6, s0, y0);
        y1 = fmaf(cdt6, s1, y1);
        if (lane == 0) {
            reinterpret_cast<float2*>(outb)[t] = make_float2(y0, y1);
        }
    }
}

extern "C" void kernel_launch(void* const* d_in, const int* in_sizes, int n_in,
                              void* d_out, int out_size, void* d_ws, size_t ws_size,
                              hipStream_t stream) {
    const float* y0 = (const float*)d_in[0];
    const float* W1 = (const float*)d_in[1];
    const float* B1 = (const float*)d_in[2];
    const float* W2 = (const float*)d_in[3];
    const float* B2 = (const float*)d_in[4];
    const float* W3 = (const float*)d_in[5];
    const float* B3 = (const float*)d_in[6];
    float* out = (float*)d_out;
    float* W2T = (float*)d_ws;   // 16 KB of workspace

    const int batch = in_sizes[0] / 2;
    const int blocks = (batch + 3) / 4;   // 4 waves (samples) per 256-thread block

    transpose_w2_kernel<<<1, 256, 0, stream>>>(W2, W2T);
    node_rk4_kernel<<<blocks, 256, 0, stream>>>(y0, W1, B1, W2T, B2, W3, B3, out, batch);
}

// Round 10
// 11286.830 us; speedup vs baseline: 9.8416x; 1.0291x over previous
//
#include <hip/hip_runtime.h>
#include <stdint.h>

#define N_STEPS 2000
#define DT_F 0.01f

typedef float f32x2 __attribute__((ext_vector_type(2)));

// tanh(x) = 1 - 2/(exp2(2x*log2e)+1): mul, exp2, add, rcp, fma = 5 VALU.
__device__ __forceinline__ float fast_tanh(float x) {
    float e = __builtin_amdgcn_exp2f(x * 2.8853900817779268f);  // e^{2x}
    float r = __builtin_amdgcn_rcpf(e + 1.0f);
    return fmaf(-2.0f, r, 1.0f);
}

template <int CTRL>
__device__ __forceinline__ float dpp_add(float v) {
    return v + __builtin_bit_cast(float, __builtin_amdgcn_update_dpp(
                   0, __builtin_bit_cast(int, v), CTRL, 0xf, 0xf, true));
}

// Every lane gets the sum of its row of 16 (all source lanes valid).
__device__ __forceinline__ float row16_sum(float v) {
    v = dpp_add<0xB1>(v);   // quad_perm [1,0,3,2]
    v = dpp_add<0x4E>(v);   // quad_perm [2,3,0,1]
    v = dpp_add<0x124>(v);  // row_ror:4
    v = dpp_add<0x128>(v);  // row_ror:8
    return v;
}

__device__ __forceinline__ float bperm_add(float v, int addr) {
    return v + __builtin_bit_cast(float, __builtin_amdgcn_ds_bpermute(
                   addr, __builtin_bit_cast(int, v)));
}

// Sum across 64 lanes, result uniform in a VGPR (no readlane, no SGPR movs).
__device__ __forceinline__ float wave_sum_u(float v, int a16, int a32) {
    v = row16_sum(v);
    v = bperm_add(v, a16);  // + other row in 32-half
    v = bperm_add(v, a32);  // + other half
    return v;
}

// One-time 64x64 transpose of W2 into workspace: W2T[j][i] = W2[i][j].
__global__ void transpose_w2_kernel(const float* __restrict__ W2,
                                    float* __restrict__ W2T) {
    for (int k = threadIdx.x; k < 64 * 64; k += 256) {
        int i = k >> 6, j = k & 63;
        W2T[j * 64 + i] = W2[k];
    }
}

// Pure-C inner loop (no inline asm): R5/R7/R9 all parked the 64 weight values
// outside arch VGPRs and the 32 asm PKFMA blocks' "v" constraints forced a
// copy (or reload) per use (~+130 cyc/eval). __builtin_elementwise_fma on
// f32x2 selects v_pk_fma_f32 with AV operand classes -> works directly from
// VGPR or AGPR, no copies, and leaves the allocator free to keep w2p resident
// under the (256,3) ~168-reg budget.
__global__ __launch_bounds__(256, 3) void node_rk4_kernel(
    const float* __restrict__ y0_in,
    const float* __restrict__ W1, const float* __restrict__ B1,
    const float* __restrict__ W2T, const float* __restrict__ B2,
    const float* __restrict__ W3, const float* __restrict__ B3,
    float* __restrict__ out, int batch)
{
    __shared__ __align__(16) float hl_all[4][64];

    const int tid  = threadIdx.x;
    const int lane = tid & 63;
    const int wib  = tid >> 6;                 // wave-in-block 0..3
    const int b    = blockIdx.x * 4 + wib;     // sample id
    if (b >= batch) return;

    const int j = lane;
    const float w1_0 = W1[j], w1_1 = W1[64 + j];
    const float b1v  = B1[j], b2v = B2[j];
    const float w3_0 = W3[2 * j], w3_1 = W3[2 * j + 1];
    // Fold b3 into lane 0's pre-reduction term.
    const float b3l0 = (lane == 0) ? B3[0] : 0.0f;
    const float b3l1 = (lane == 0) ? B3[1] : 0.0f;

    // Lane j's weight column -> 32 f32x2 pairs, loaded once (contiguous).
    f32x2 w2p[32];
    {
        const f32x2* __restrict__ w2c = (const f32x2*)(W2T + (j << 6));
        #pragma unroll
        for (int i = 0; i < 32; ++i) w2p[i] = w2c[i];
    }

    // bpermute lane-select addresses (bytes = lane*4).
    const int a16 = ((lane ^ 16) << 2);
    const int a32 = ((lane ^ 32) << 2);

    float y0 = y0_in[2 * b + 0];
    float y1 = y0_in[2 * b + 1];

    float* outb = out + (size_t)b * (2 * (N_STEPS + 1));
    if (lane == 0) {
        reinterpret_cast<float2*>(outb)[0] = make_float2(y0, y1);
    }

    const float chdt = 0.5f * DT_F, cdt = DT_F, cdt6 = DT_F / 6.0f;

    float* hl = hl_all[wib];
    const f32x2* hp2 = (const f32x2*)hl;

    // net: wave-uniform (yi0,yi1) -> wave-uniform VGPR (o0,o1); lane j owns unit j.
    auto net = [&](float yi0, float yi1, float& o0, float& o1) {
        float pre = fmaf(yi0, w1_0, fmaf(yi1, w1_1, b1v));
        float h1  = fast_tanh(pre);
        hl[lane] = h1;
        __builtin_amdgcn_wave_barrier();   // write -> read ordering (in-wave DS order)

        f32x2 acc0 = (f32x2){b2v, 0.0f};
        f32x2 acc1 = (f32x2){0.0f, 0.0f};
        f32x2 acc2 = (f32x2){0.0f, 0.0f};
        f32x2 acc3 = (f32x2){0.0f, 0.0f};
        #pragma unroll
        for (int i = 0; i < 32; i += 4) {
            acc0 = __builtin_elementwise_fma(hp2[i + 0], w2p[i + 0], acc0);
            acc1 = __builtin_elementwise_fma(hp2[i + 1], w2p[i + 1], acc1);
            acc2 = __builtin_elementwise_fma(hp2[i + 2], w2p[i + 2], acc2);
            acc3 = __builtin_elementwise_fma(hp2[i + 3], w2p[i + 3], acc3);
        }
        __builtin_amdgcn_wave_barrier();   // reads done before next eval's write

        f32x2 s = (acc0 + acc1) + (acc2 + acc3);
        float h2 = fast_tanh(s.x + s.y);
        float p0 = fmaf(h2, w3_0, b3l0);
        float p1 = fmaf(h2, w3_1, b3l1);
        o0 = wave_sum_u(p0, a16, a32);
        o1 = wave_sum_u(p1, a16, a32);
    };

    for (int t = 1; t <= N_STEPS; ++t) {
        float k10, k11, k20, k21, k30, k31, k40, k41;
        net(y0, y1, k10, k11);
        net(fmaf(chdt, k10, y0), fmaf(chdt, k11, y1), k20, k21);
        net(fmaf(chdt, k20, y0), fmaf(chdt, k21, y1), k30, k31);
        net(fmaf(cdt,  k30, y0), fmaf(cdt,  k31, y1), k40, k41);
        float s0 = (k10 + k40) + 2.0f * (k20 + k30);
        float s1 = (k11 + k41) + 2.0f * (k21 + k31);
        y0 = fmaf(cdt6, s0, y0);
        y1 = fmaf(cdt6, s1, y1);
        if (lane == 0) {
            reinterpret_cast<float2*>(outb)[t] = make_float2(y0, y1);
        }
    }
}

extern "C" void kernel_launch(void* const* d_in, const int* in_sizes, int n_in,
                              void* d_out, int out_size, void* d_ws, size_t ws_size,
                              hipStream_t stream) {
    const float* y0 = (const float*)d_in[0];
    const float* W1 = (const float*)d_in[1];
    const float* B1 = (const float*)d_in[2];
    const float* W2 = (const float*)d_in[3];
    const float* B2 = (const float*)d_in[4];
    const float* W3 = (const float*)d_in[5];
    const float* B3 = (const float*)d_in[6];
    float* out = (float*)d_out;
    float* W2T = (float*)d_ws;   // 16 KB of workspace

    const int batch = in_sizes[0] / 2;
    const int blocks = (batch + 3) / 4;   // 4 waves (samples) per 256-thread block

    transpose_w2_kernel<<<1, 256, 0, stream>>>(W2, W2T);
    node_rk4_kernel<<<blocks, 256, 0, stream>>>(y0, W1, B1, W2T, B2, W3, B3, out, batch);
}

// Round 11
// 11277.121 us; speedup vs baseline: 9.8501x; 1.0009x over previous
//
#include <hip/hip_runtime.h>
#include <stdint.h>

#define N_STEPS 2000
#define DT_F 0.01f

typedef float f32x2 __attribute__((ext_vector_type(2)));

// tanh(x) = 1 - 2/(exp2(2x*log2e)+1): mul, exp2, add, rcp, fma = 5 VALU.
__device__ __forceinline__ float fast_tanh(float x) {
    float e = __builtin_amdgcn_exp2f(x * 2.8853900817779268f);  // e^{2x}
    float r = __builtin_amdgcn_rcpf(e + 1.0f);
    return fmaf(-2.0f, r, 1.0f);
}

template <int CTRL>
__device__ __forceinline__ float dpp_add(float v) {
    return v + __builtin_bit_cast(float, __builtin_amdgcn_update_dpp(
                   0, __builtin_bit_cast(int, v), CTRL, 0xf, 0xf, true));
}

// Every lane gets the sum of its row of 16 (all source lanes valid).
__device__ __forceinline__ float row16_sum(float v) {
    v = dpp_add<0xB1>(v);   // quad_perm [1,0,3,2]
    v = dpp_add<0x4E>(v);   // quad_perm [2,3,0,1]
    v = dpp_add<0x124>(v);  // row_ror:4
    v = dpp_add<0x128>(v);  // row_ror:8
    return v;
}

__device__ __forceinline__ float bperm_add(float v, int addr) {
    return v + __builtin_bit_cast(float, __builtin_amdgcn_ds_bpermute(
                   addr, __builtin_bit_cast(int, v)));
}

// Sum across 64 lanes, result uniform in a VGPR (no readlane, no SGPR movs).
__device__ __forceinline__ float wave_sum_u(float v, int a16, int a32) {
    v = row16_sum(v);
    v = bperm_add(v, a16);  // + other row in 32-half
    v = bperm_add(v, a32);  // + other half
    return v;
}

// One-time 64x64 transpose of W2 into workspace: W2T[j][i] = W2[i][j].
__global__ void transpose_w2_kernel(const float* __restrict__ W2,
                                    float* __restrict__ W2T) {
    for (int k = threadIdx.x; k < 64 * 64; k += 256) {
        int i = k >> 6, j = k & 63;
        W2T[j * 64 + i] = W2[k];
    }
}

// KEY CHANGE vs R10: amdgpu_waves_per_eu(4,4) — min AND MAX occupancy.
// __launch_bounds__'s 2nd arg sets only the MIN; the scheduler still targets
// 8 waves/EU (64-reg pressure), which parked the 64 weight values in AGPRs
// with a v_accvgpr_read copy per use (~128 cyc/eval — the constant gap in
// R5/R7/R9/R10: VGPR_Count 56, 327-362 busy-cyc/eval, occupancy 3.3 waves).
// With max=4 the target is 4 waves/EU -> 128-reg budget; the ~118-reg
// working set (64 weights + ~54 state) fits in arch VGPRs, no copies.
__global__ __attribute__((amdgpu_flat_work_group_size(256, 256),
                          amdgpu_waves_per_eu(4, 4)))
void node_rk4_kernel(
    const float* __restrict__ y0_in,
    const float* __restrict__ W1, const float* __restrict__ B1,
    const float* __restrict__ W2T, const float* __restrict__ B2,
    const float* __restrict__ W3, const float* __restrict__ B3,
    float* __restrict__ out, int batch)
{
    __shared__ __align__(16) float hl_all[4][64];

    const int tid  = threadIdx.x;
    const int lane = tid & 63;
    const int wib  = tid >> 6;                 // wave-in-block 0..3
    const int b    = blockIdx.x * 4 + wib;     // sample id
    if (b >= batch) return;

    const int j = lane;
    const float w1_0 = W1[j], w1_1 = W1[64 + j];
    const float b1v  = B1[j], b2v = B2[j];
    const float w3_0 = W3[2 * j], w3_1 = W3[2 * j + 1];
    // Fold b3 into lane 0's pre-reduction term.
    const float b3l0 = (lane == 0) ? B3[0] : 0.0f;
    const float b3l1 = (lane == 0) ? B3[1] : 0.0f;

    // Lane j's weight column -> 32 f32x2 pairs, loaded once (contiguous).
    f32x2 w2p[32];
    {
        const f32x2* __restrict__ w2c = (const f32x2*)(W2T + (j << 6));
        #pragma unroll
        for (int i = 0; i < 32; ++i) w2p[i] = w2c[i];
    }

    // bpermute lane-select addresses (bytes = lane*4).
    const int a16 = ((lane ^ 16) << 2);
    const int a32 = ((lane ^ 32) << 2);

    float y0 = y0_in[2 * b + 0];
    float y1 = y0_in[2 * b + 1];

    float* outb = out + (size_t)b * (2 * (N_STEPS + 1));
    if (lane == 0) {
        reinterpret_cast<float2*>(outb)[0] = make_float2(y0, y1);
    }

    const float chdt = 0.5f * DT_F, cdt = DT_F, cdt6 = DT_F / 6.0f;

    float* hl = hl_all[wib];
    const f32x2* hp2 = (const f32x2*)hl;

    // net: wave-uniform (yi0,yi1) -> wave-uniform VGPR (o0,o1); lane j owns unit j.
    auto net = [&](float yi0, float yi1, float& o0, float& o1) {
        float pre = fmaf(yi0, w1_0, fmaf(yi1, w1_1, b1v));
        float h1  = fast_tanh(pre);
        hl[lane] = h1;
        __builtin_amdgcn_wave_barrier();   // write -> read ordering (in-wave DS order)

        f32x2 acc0 = (f32x2){b2v, 0.0f};
        f32x2 acc1 = (f32x2){0.0f, 0.0f};
        f32x2 acc2 = (f32x2){0.0f, 0.0f};
        f32x2 acc3 = (f32x2){0.0f, 0.0f};
        #pragma unroll
        for (int i = 0; i < 32; i += 4) {
            acc0 = __builtin_elementwise_fma(hp2[i + 0], w2p[i + 0], acc0);
            acc1 = __builtin_elementwise_fma(hp2[i + 1], w2p[i + 1], acc1);
            acc2 = __builtin_elementwise_fma(hp2[i + 2], w2p[i + 2], acc2);
            acc3 = __builtin_elementwise_fma(hp2[i + 3], w2p[i + 3], acc3);
        }
        __builtin_amdgcn_wave_barrier();   // reads done before next eval's write

        f32x2 s = (acc0 + acc1) + (acc2 + acc3);
        float h2 = fast_tanh(s.x + s.y);
        float p0 = fmaf(h2, w3_0, b3l0);
        float p1 = fmaf(h2, w3_1, b3l1);
        o0 = wave_sum_u(p0, a16, a32);
        o1 = wave_sum_u(p1, a16, a32);
    };

    for (int t = 1; t <= N_STEPS; ++t) {
        float k10, k11, k20, k21, k30, k31, k40, k41;
        net(y0, y1, k10, k11);
        net(fmaf(chdt, k10, y0), fmaf(chdt, k11, y1), k20, k21);
        net(fmaf(chdt, k20, y0), fmaf(chdt, k21, y1), k30, k31);
        net(fmaf(cdt,  k30, y0), fmaf(cdt,  k31, y1), k40, k41);
        float s0 = (k10 + k40) + 2.0f * (k20 + k30);
        float s1 = (k11 + k41) + 2.0f * (k21 + k31);
        y0 = fmaf(cdt6, s0, y0);
        y1 = fmaf(cdt6, s1, y1);
        if (lane == 0) {
            reinterpret_cast<float2*>(outb)[t] = make_float2(y0, y1);
        }
    }
}

extern "C" void kernel_launch(void* const* d_in, const int* in_sizes, int n_in,
                              void* d_out, int out_size, void* d_ws, size_t ws_size,
                              hipStream_t stream) {
    const float* y0 = (const float*)d_in[0];
    const float* W1 = (const float*)d_in[1];
    const float* B1 = (const float*)d_in[2];
    const float* W2 = (const float*)d_in[3];
    const float* B2 = (const float*)d_in[4];
    const float* W3 = (const float*)d_in[5];
    const float* B3 = (const float*)d_in[6];
    float* out = (float*)d_out;
    float* W2T = (float*)d_ws;   // 16 KB of workspace

    const int batch = in_sizes[0] / 2;
    const int blocks = (batch + 3) / 4;   // 4 waves (samples) per 256-thread block

    transpose_w2_kernel<<<1, 256, 0, stream>>>(W2, W2T);
    node_rk4_kernel<<<blocks, 256, 0, stream>>>(y0, W1, B1, W2T, B2, W3, B3, out, batch);
}